// Round 22
// baseline (189.142 us; speedup 1.0000x reference)
//
#include <hip/hip_runtime.h>

#define T_LEN  4096
#define KS     16
#define NSEG   16          // T segments (256 output steps each)
#define SEG_CH 16          // output chunks per segment
#define WARM_CH 24         // 384 warm-up steps (geometry validated R16-R21)

#define ALPHA_F 0.9048374180359595f
#define BETA_F  0.09516258196404048f
#define THETA_F 0.5f

// Full-wave (64-lane) max, result in ALL lanes. Verbatim from the passing
// R3-R21 kernels (manual s_nop hazard handling inside asm).
__device__ __forceinline__ float wave64_max_all(float v) {
  float m, t;
  asm("s_nop 1\n\t"
      "v_max_f32 %0, %2, %2 quad_perm:[1,0,3,2] row_mask:0xf bank_mask:0xf\n\t"
      "s_nop 1\n\t"
      "v_max_f32 %0, %0, %0 quad_perm:[2,3,0,1] row_mask:0xf bank_mask:0xf\n\t"
      "s_nop 1\n\t"
      "v_max_f32 %0, %0, %0 row_half_mirror row_mask:0xf bank_mask:0xf\n\t"
      "s_nop 1\n\t"
      "v_max_f32 %0, %0, %0 row_mirror row_mask:0xf bank_mask:0xf\n\t"
      "v_mov_b32 %1, %0\n\t"
      "s_nop 1\n\t"
      "v_permlane32_swap_b32 %1, %0\n\t"
      "s_nop 1\n\t"
      "v_max_f32 %0, %0, %1\n\t"
      "v_mov_b32 %1, %0\n\t"
      "s_nop 1\n\t"
      "v_permlane16_swap_b32 %1, %0\n\t"
      "s_nop 1\n\t"
      "v_max_f32 %0, %0, %1"
      : "=&v"(m), "=&v"(t)
      : "v"(v));
  return m;
}

__global__ __launch_bounds__(128, 8)
void convlif_wta_kernel(const float* __restrict__ x, const float* __restrict__ W,
                        float* __restrict__ out) {
  const int blk  = blockIdx.x;
  const int b    = blk >> 4;          // batch
  const int seg  = blk & (NSEG - 1);  // time segment
  const int wave = threadIdx.x >> 6;  // 0/1: ping-pong roles per chunk
  const int lane = threadIdx.x & 63;  // channel k

  const int cout0  = seg * SEG_CH;                                  // first output chunk
  const int cstart = (cout0 > WARM_CH) ? (cout0 - WARM_CH) : 0;     // warm-up start
  const int cend   = cout0 + SEG_CH;
  const int nch    = cend - cstart;   // 40 (seg>0) or 16 (seg 0)

  __shared__ float vbuf[2][64];       // v handoff ring (2 slots)

  // per-lane conv weights W[k][0..15] (verbatim)
  float w[KS];
  {
    const float4* w4 = reinterpret_cast<const float4*>(W + lane * KS);
    #pragma unroll
    for (int q = 0; q < 4; ++q) {
      float4 a = w4[q];
      w[4*q+0] = a.x; w[4*q+1] = a.y; w[4*q+2] = a.z; w[4*q+3] = a.w;
    }
  }

  const float4* xv4 = reinterpret_cast<const float4*>(x + (size_t)b * T_LEN);
  float* orow = out + ((size_t)(b * 64 + lane)) * T_LEN;   // this lane's channel row

  float u[16];   // conv results for my NEXT active chunk (lives across barrier)

  // conv for chunk c — verbatim summation order of all passing rounds.
  auto conv_chunk = [&](int c) {
    float xf[32];
    if (c == 0) {
      #pragma unroll
      for (int m = 0; m < 16; ++m) xf[m] = 0.0f;
    } else {
      const int b4 = 4 * c - 4;
      #pragma unroll
      for (int q = 0; q < 4; ++q) {
        float4 a = xv4[b4 + q];
        xf[4*q+0] = a.x; xf[4*q+1] = a.y; xf[4*q+2] = a.z; xf[4*q+3] = a.w;
      }
    }
    #pragma unroll
    for (int q = 0; q < 4; ++q) {
      float4 a = xv4[4*c + q];
      xf[16+4*q+0] = a.x; xf[16+4*q+1] = a.y;
      xf[16+4*q+2] = a.z; xf[16+4*q+3] = a.w;
    }
    #pragma unroll
    for (int i = 0; i < 16; ++i) {
      float acc = w[0] * xf[1 + i];
      #pragma unroll
      for (int j = 1; j < KS; ++j) acc = fmaf(w[j], xf[1 + i + j], acc);
      u[i] = BETA_F * acc;
    }
  };

  // prologue: wave 0 computes conv for the first chunk (its s=0 active turn)
  if (wave == 0) conv_chunk(cstart);

  for (int s = 0; s < nch; ++s) {
    const int c = cstart + s;
    if ((s & 1) == wave) {
      // ---------- active: LIF + WTA on this chunk (verbatim R16/R18 body) -
      float v = (s == 0) ? 0.0f : vbuf[(s - 1) & 1][lane];
      float sv[16];
      #pragma unroll
      for (int i = 0; i < 16; ++i) {
        float vr = fmaf(ALPHA_F, v, u[i]);
        float vm = vr - THETA_F;
        unsigned long long sp = __ballot(vr >= THETA_F);
        bool c1 = (vr >= THETA_F);
        sv[i] = c1 ? 1.0f : 0.0f;
        v     = c1 ? vm : vr;
        if (__builtin_expect((sp & (sp - 1ull)) != 0ull, 0)) {
          float m = wave64_max_all(vr);
          unsigned long long eq = __ballot(vr == m);
          bool win = (lane == __builtin_ctzll(eq));
          sv[i] = win ? 1.0f : 0.0f;
          v     = win ? vm : vr;
        }
      }
      vbuf[s & 1][lane] = v;            // hand v to the other wave

      if (c >= cout0) {                 // store only in the output window
        float4* p = reinterpret_cast<float4*>(orow + (size_t)c * 16);
        p[0] = make_float4(sv[0],  sv[1],  sv[2],  sv[3]);
        p[1] = make_float4(sv[4],  sv[5],  sv[6],  sv[7]);
        p[2] = make_float4(sv[8],  sv[9],  sv[10], sv[11]);
        p[3] = make_float4(sv[12], sv[13], sv[14], sv[15]);
      }
    } else {
      // ---------- passive: conv my next chunk (c+1) -----------------------
      if (c + 1 < cend) conv_chunk(c + 1);
    }
    __syncthreads();   // orders vbuf write -> next iteration's read
  }
}

extern "C" void kernel_launch(void* const* d_in, const int* in_sizes, int n_in,
                              void* d_out, int out_size, void* d_ws, size_t ws_size,
                              hipStream_t stream) {
  const float* x   = (const float*)d_in[0];
  const float* W   = (const float*)d_in[1];
  float*       out = (float*)d_out;
  convlif_wta_kernel<<<dim3(256 * NSEG), dim3(128), 0, stream>>>(x, W, out);
}

// Round 23
// 130.042 us; speedup vs baseline: 1.4545x; 1.4545x over previous
//
#include <hip/hip_runtime.h>

#define T_LEN  4096
#define KS     16
#define NSEG   16          // T segments (256 output steps each)
#define SEG_CH 16          // output chunks per segment
#define WARM_CH 24         // 384 warm-up steps (geometry validated R16-R21)

#define ALPHA_F 0.9048374180359595f
#define BETA_F  0.09516258196404048f
#define THETA_F 0.5f

typedef float f32x2 __attribute__((ext_vector_type(2)));

// packed 2xf32 ops (VOP3P). Each half is an IEEE-exact mul/fma -> per-output
// arithmetic identical to the scalar version (R21-proven).
__device__ __forceinline__ f32x2 pk_mul(f32x2 a, f32x2 b) {
  f32x2 d;
  asm("v_pk_mul_f32 %0, %1, %2" : "=v"(d) : "v"(a), "v"(b));
  return d;
}
__device__ __forceinline__ f32x2 pk_fma(f32x2 a, f32x2 b, f32x2 c) {
  f32x2 d;
  asm("v_pk_fma_f32 %0, %1, %2, %3" : "=v"(d) : "v"(a), "v"(b), "v"(c));
  return d;
}

// Full-wave (64-lane) max, result in ALL lanes. Verbatim from the passing
// R3-R22 kernels (manual s_nop hazard handling inside asm).
__device__ __forceinline__ float wave64_max_all(float v) {
  float m, t;
  asm("s_nop 1\n\t"
      "v_max_f32 %0, %2, %2 quad_perm:[1,0,3,2] row_mask:0xf bank_mask:0xf\n\t"
      "s_nop 1\n\t"
      "v_max_f32 %0, %0, %0 quad_perm:[2,3,0,1] row_mask:0xf bank_mask:0xf\n\t"
      "s_nop 1\n\t"
      "v_max_f32 %0, %0, %0 row_half_mirror row_mask:0xf bank_mask:0xf\n\t"
      "s_nop 1\n\t"
      "v_max_f32 %0, %0, %0 row_mirror row_mask:0xf bank_mask:0xf\n\t"
      "v_mov_b32 %1, %0\n\t"
      "s_nop 1\n\t"
      "v_permlane32_swap_b32 %1, %0\n\t"
      "s_nop 1\n\t"
      "v_max_f32 %0, %0, %1\n\t"
      "v_mov_b32 %1, %0\n\t"
      "s_nop 1\n\t"
      "v_permlane16_swap_b32 %1, %0\n\t"
      "s_nop 1\n\t"
      "v_max_f32 %0, %0, %1"
      : "=&v"(m), "=&v"(t)
      : "v"(v));
  return m;
}

__global__ __launch_bounds__(64, 4)
void convlif_wta_kernel(const float* __restrict__ x, const float* __restrict__ W,
                        float* __restrict__ out) {
  const int blk  = blockIdx.x;
  const int b    = blk >> 4;          // batch
  const int seg  = blk & (NSEG - 1);  // time segment
  const int lane = threadIdx.x;       // channel k

  const int cout0  = seg * SEG_CH;                                  // first output chunk
  const int cstart = (cout0 > WARM_CH) ? (cout0 - WARM_CH) : 0;     // warm-up start
  const int cend   = cout0 + SEG_CH;

  // per-lane conv weights, pre-broadcast into packed pairs wp[j] = (w[j], w[j])
  f32x2 wp[KS];
  {
    const float4* w4 = reinterpret_cast<const float4*>(W + lane * KS);
    #pragma unroll
    for (int q = 0; q < 4; ++q) {
      float4 a = w4[q];
      wp[4*q+0] = (f32x2){a.x, a.x}; wp[4*q+1] = (f32x2){a.y, a.y};
      wp[4*q+2] = (f32x2){a.z, a.z}; wp[4*q+3] = (f32x2){a.w, a.w};
    }
  }

  const float4* xv4 = reinterpret_cast<const float4*>(x + (size_t)b * T_LEN);
  float* orow = out + ((size_t)(b * 64 + lane)) * T_LEN;   // this lane's channel row

  f32x2 a2[8];   // conv pair-sums (u_raw[2m], u_raw[2m+1]) for current chunk

  // conv for chunk c (verbatim R21, bit-identical per-output j-order to the
  // scalar conv of all passing rounds). xf[m] = x[16c-16+m], x[<0]=0.
  // xp[n] = (xf[2n], xf[2n+1]); yp[n] = (xf[2n+1], xf[2n+2]).
  // Tap j for outputs (u[2m],u[2m+1]): j even -> yp[m+j/2], j odd -> xp[m+(j+1)/2].
  auto conv_chunk = [&](int c) {
    f32x2 xp[16];
    if (c == 0) {
      #pragma unroll
      for (int n = 0; n < 8; ++n) xp[n] = (f32x2){0.0f, 0.0f};
    } else {
      const int b4 = 4 * c - 4;
      #pragma unroll
      for (int q = 0; q < 4; ++q) {
        float4 a = xv4[b4 + q];
        xp[2*q+0] = (f32x2){a.x, a.y};
        xp[2*q+1] = (f32x2){a.z, a.w};
      }
    }
    #pragma unroll
    for (int q = 0; q < 4; ++q) {
      float4 a = xv4[4*c + q];
      xp[8+2*q+0] = (f32x2){a.x, a.y};
      xp[8+2*q+1] = (f32x2){a.z, a.w};
    }
    f32x2 yp[15];
    #pragma unroll
    for (int n = 0; n < 15; ++n) yp[n] = (f32x2){xp[n].y, xp[n+1].x};

    #pragma unroll
    for (int m = 0; m < 8; ++m) {
      f32x2 acc = pk_mul(wp[0], yp[m]);                  // j=0
      #pragma unroll
      for (int j = 1; j < KS; ++j)
        acc = pk_fma(wp[j], (j & 1) ? xp[m + (j+1)/2] : yp[m + j/2], acc);
      a2[m] = acc;
    }
  };

  float v = 0.0f;   // exact for seg 0-1 (warm-up reaches t=0); speculative else

  // ---------------- phase 1: warm-up (no sv, no stores) -------------------
  for (int c = cstart; c < cout0; ++c) {
    conv_chunk(c);
    #pragma unroll
    for (int i = 0; i < 16; ++i) {
      float ui = BETA_F * ((i & 1) ? a2[i >> 1].y : a2[i >> 1].x);  // == u[i]
      float vr = fmaf(ALPHA_F, v, ui);
      float vm = vr - THETA_F;
      unsigned long long sp = __ballot(vr >= THETA_F);
      bool c1 = (vr >= THETA_F);
      v = c1 ? vm : vr;
      if (__builtin_expect((sp & (sp - 1ull)) != 0ull, 0)) {
        float m = wave64_max_all(vr);
        unsigned long long eq = __ballot(vr == m);
        bool win = (lane == __builtin_ctzll(eq));
        v = win ? vm : vr;
      }
    }
  }

  // ---------------- phase 2: output window --------------------------------
  for (int c = cout0; c < cend; ++c) {
    conv_chunk(c);
    float sv[16];
    #pragma unroll
    for (int i = 0; i < 16; ++i) {
      float ui = BETA_F * ((i & 1) ? a2[i >> 1].y : a2[i >> 1].x);  // == u[i]
      float vr = fmaf(ALPHA_F, v, ui);
      float vm = vr - THETA_F;
      unsigned long long sp = __ballot(vr >= THETA_F);
      bool c1 = (vr >= THETA_F);
      sv[i] = c1 ? 1.0f : 0.0f;
      v     = c1 ? vm : vr;
      if (__builtin_expect((sp & (sp - 1ull)) != 0ull, 0)) {
        float m = wave64_max_all(vr);
        unsigned long long eq = __ballot(vr == m);
        bool win = (lane == __builtin_ctzll(eq));
        sv[i] = win ? 1.0f : 0.0f;
        v     = win ? vm : vr;
      }
    }

    float4* p = reinterpret_cast<float4*>(orow + (size_t)c * 16);
    p[0] = make_float4(sv[0],  sv[1],  sv[2],  sv[3]);
    p[1] = make_float4(sv[4],  sv[5],  sv[6],  sv[7]);
    p[2] = make_float4(sv[8],  sv[9],  sv[10], sv[11]);
    p[3] = make_float4(sv[12], sv[13], sv[14], sv[15]);
  }
}

extern "C" void kernel_launch(void* const* d_in, const int* in_sizes, int n_in,
                              void* d_out, int out_size, void* d_ws, size_t ws_size,
                              hipStream_t stream) {
  const float* x   = (const float*)d_in[0];
  const float* W   = (const float*)d_in[1];
  float*       out = (float*)d_out;
  convlif_wta_kernel<<<dim3(256 * NSEG), dim3(64), 0, stream>>>(x, W, out);
}

// Round 24
// 109.738 us; speedup vs baseline: 1.7236x; 1.1850x over previous
//
#include <hip/hip_runtime.h>

#define T_LEN  4096
#define KS     16
#define NSEG   8           // T segments (512 output steps each)
#define SEG_CH 32          // output chunks per segment
#define WARM_CH 24         // 384 warm-up steps (geometry validated R17-R21)
#define USTRIDE 18         // u-row stride in dwords: 2-way bank aliasing, 8B-aligned

#define ALPHA_F 0.9048374180359595f
#define BETA_F  0.09516258196404048f
#define THETA_F 0.5f

// Full-wave (64-lane) max, result in ALL lanes. Verbatim from the passing
// R3-R23 kernels (manual s_nop hazard handling inside asm).
__device__ __forceinline__ float wave64_max_all(float v) {
  float m, t;
  asm("s_nop 1\n\t"
      "v_max_f32 %0, %2, %2 quad_perm:[1,0,3,2] row_mask:0xf bank_mask:0xf\n\t"
      "s_nop 1\n\t"
      "v_max_f32 %0, %0, %0 quad_perm:[2,3,0,1] row_mask:0xf bank_mask:0xf\n\t"
      "s_nop 1\n\t"
      "v_max_f32 %0, %0, %0 row_half_mirror row_mask:0xf bank_mask:0xf\n\t"
      "s_nop 1\n\t"
      "v_max_f32 %0, %0, %0 row_mirror row_mask:0xf bank_mask:0xf\n\t"
      "v_mov_b32 %1, %0\n\t"
      "s_nop 1\n\t"
      "v_permlane32_swap_b32 %1, %0\n\t"
      "s_nop 1\n\t"
      "v_max_f32 %0, %0, %1\n\t"
      "v_mov_b32 %1, %0\n\t"
      "s_nop 1\n\t"
      "v_permlane16_swap_b32 %1, %0\n\t"
      "s_nop 1\n\t"
      "v_max_f32 %0, %0, %1"
      : "=&v"(m), "=&v"(t)
      : "v"(v));
  return m;
}

__global__ __launch_bounds__(128, 4)
void convlif_wta_kernel(const float* __restrict__ x, const float* __restrict__ W,
                        float* __restrict__ out) {
  const int blk  = blockIdx.x;
  const int b    = blk >> 3;          // batch
  const int seg  = blk & (NSEG - 1);  // time segment
  const int wave = threadIdx.x >> 6;  // 0 = consumer (LIF), 1 = producer (conv)
  const int lane = threadIdx.x & 63;  // channel k

  const int cout0  = seg * SEG_CH;                                  // first output chunk
  const int cstart = (cout0 > WARM_CH) ? (cout0 - WARM_CH) : 0;     // warm-up start
  const int cend   = cout0 + SEG_CH;
  const int npair  = (cend - cstart) >> 1;   // 28 (seg>0) or 16 (seg 0); nch is even

  // u handoff ring: [slot][chunk-of-pair][lane][i]; stride 18 dwords ->
  // float2 8B-aligned, 2-way bank aliasing (free). 18 KB/block -> 8 blocks/CU.
  __shared__ float dbuf[2][2][64][USTRIDE];

  const float4* xv4 = reinterpret_cast<const float4*>(x + (size_t)b * T_LEN);
  float* orow = out + ((size_t)(b * 64 + lane)) * T_LEN;   // this lane's channel row

  if (wave == 1) {
    // ================= producer: conv pairs into the LDS ring =============
    float w[KS];
    {
      const float4* w4 = reinterpret_cast<const float4*>(W + lane * KS);
      #pragma unroll
      for (int q = 0; q < 4; ++q) {
        float4 a = w4[q];
        w[4*q+0] = a.x; w[4*q+1] = a.y; w[4*q+2] = a.z; w[4*q+3] = a.w;
      }
    }

    for (int p = 0; p <= npair; ++p) {
      if (p < npair) {
        #pragma unroll
        for (int ch = 0; ch < 2; ++ch) {
          const int c = cstart + 2 * p + ch;
          // conv for chunk c — verbatim summation order of all passing rounds
          float xf[32];
          if (c == 0) {
            #pragma unroll
            for (int m = 0; m < 16; ++m) xf[m] = 0.0f;
          } else {
            const int b4 = 4 * c - 4;
            #pragma unroll
            for (int q = 0; q < 4; ++q) {
              float4 a = xv4[b4 + q];
              xf[4*q+0] = a.x; xf[4*q+1] = a.y; xf[4*q+2] = a.z; xf[4*q+3] = a.w;
            }
          }
          #pragma unroll
          for (int q = 0; q < 4; ++q) {
            float4 a = xv4[4*c + q];
            xf[16+4*q+0] = a.x; xf[16+4*q+1] = a.y;
            xf[16+4*q+2] = a.z; xf[16+4*q+3] = a.w;
          }

          float* ur = &dbuf[p & 1][ch][lane][0];
          #pragma unroll
          for (int i = 0; i < 16; i += 2) {
            float acc0 = w[0] * xf[1 + i];
            #pragma unroll
            for (int j = 1; j < KS; ++j) acc0 = fmaf(w[j], xf[1 + i + j], acc0);
            float acc1 = w[0] * xf[2 + i];
            #pragma unroll
            for (int j = 1; j < KS; ++j) acc1 = fmaf(w[j], xf[2 + i + j], acc1);
            *reinterpret_cast<float2*>(ur + i) =
                make_float2(BETA_F * acc0, BETA_F * acc1);   // u[i], u[i+1]
          }
        }
      }
      __syncthreads();   // pair p published; consumer reads it next interval
    }
  } else {
    // ================= consumer: serial LIF + WTA over pairs ==============
    float v = 0.0f;      // exact for seg 0 (no warm); speculative else

    for (int p = 0; p <= npair; ++p) {
      if (p >= 1) {
        const int slot = (p - 1) & 1;
        #pragma unroll
        for (int ch = 0; ch < 2; ++ch) {
          const int c = cstart + 2 * (p - 1) + ch;

          // load this chunk's u from the ring (8 x float2, latency-hidden)
          float u[16];
          {
            const float* ur = &dbuf[slot][ch][lane][0];
            #pragma unroll
            for (int i = 0; i < 16; i += 2) {
              float2 t2 = *reinterpret_cast<const float2*>(ur + i);
              u[i] = t2.x; u[i + 1] = t2.y;
            }
          }

          // verbatim R16/R18/R21 LIF+WTA body (blind apply + rare repair)
          float sv[16];
          #pragma unroll
          for (int i = 0; i < 16; ++i) {
            float vr = fmaf(ALPHA_F, v, u[i]);
            float vm = vr - THETA_F;
            unsigned long long sp = __ballot(vr >= THETA_F);
            bool c1 = (vr >= THETA_F);
            sv[i] = c1 ? 1.0f : 0.0f;
            v     = c1 ? vm : vr;
            if (__builtin_expect((sp & (sp - 1ull)) != 0ull, 0)) {
              float m = wave64_max_all(vr);
              unsigned long long eq = __ballot(vr == m);
              bool win = (lane == __builtin_ctzll(eq));
              sv[i] = win ? 1.0f : 0.0f;
              v     = win ? vm : vr;
            }
          }

          if (c >= cout0) {               // store only in the output window
            float4* pp = reinterpret_cast<float4*>(orow + (size_t)c * 16);
            pp[0] = make_float4(sv[0],  sv[1],  sv[2],  sv[3]);
            pp[1] = make_float4(sv[4],  sv[5],  sv[6],  sv[7]);
            pp[2] = make_float4(sv[8],  sv[9],  sv[10], sv[11]);
            pp[3] = make_float4(sv[12], sv[13], sv[14], sv[15]);
          }
        }
      }
      __syncthreads();   // done with slot (p-1)&1; producer may rewrite it
    }
  }
}

extern "C" void kernel_launch(void* const* d_in, const int* in_sizes, int n_in,
                              void* d_out, int out_size, void* d_ws, size_t ws_size,
                              hipStream_t stream) {
  const float* x   = (const float*)d_in[0];
  const float* W   = (const float*)d_in[1];
  float*       out = (float*)d_out;
  convlif_wta_kernel<<<dim3(256 * NSEG), dim3(128), 0, stream>>>(x, W, out);
}